// Round 1
// baseline (9202.643 us; speedup 1.0000x reference)
//
#include <hip/hip_runtime.h>

// ForwardWarp: 4-corner gaussian-weighted scatter-add (splatting).
// img: (N=8, C=3, H=1024, W=1024) fp32
// flo: (N, 2, H, W) fp32; channel 0 = column shift (yf), channel 1 = row shift (xf)
// outputs: imgw (N,C,H,W) then onew (N,C,H,W), concatenated flat in d_out.

#define NN 8
#define CC 3
#define HH 1024
#define WW 1024
#define HW (HH * WW)

__global__ __launch_bounds__(256) void fwarp_kernel(
    const float* __restrict__ img, const float* __restrict__ flo,
    float* __restrict__ imgw, float* __restrict__ onew)
{
    const int idx = blockIdx.x * 256 + threadIdx.x;   // over N*H*W = 8M exactly
    const int wi = idx & (WW - 1);
    const int hi = (idx >> 10) & (HH - 1);
    const int n  = idx >> 20;

    const long pix = (long)hi * WW + wi;
    const long flo_base = (long)(n * 2) * HW + pix;
    const float yf = flo[flo_base];        // column shift
    const float xf = flo[flo_base + HW];   // row shift

    const float x1 = floorf(xf);
    const float y1 = floorf(yf);
    const float fx = xf - x1;              // in [0,1)
    const float fy = yf - y1;
    const int ix = (int)x1 + hi;           // target row of corner dx=0
    const int iy = (int)y1 + wi;           // target col of corner dy=0

    // separable gaussian corner weights
    float wx[2], wy[2];
    wx[0] = expf(-fx * fx);
    wx[1] = expf(-(fx - 1.0f) * (fx - 1.0f));
    wy[0] = expf(-fy * fy);
    wy[1] = expf(-(fy - 1.0f) * (fy - 1.0f));

    // channel values at source pixel
    float v[CC];
#pragma unroll
    for (int c = 0; c < CC; ++c)
        v[c] = img[(long)(n * CC + c) * HW + pix];

#pragma unroll
    for (int dx = 0; dx < 2; ++dx) {
        const int rx = ix + dx;
        if (rx < 0 || rx >= HH) continue;
#pragma unroll
        for (int dy = 0; dy < 2; ++dy) {
            const int ry = iy + dy;
            if (ry < 0 || ry >= WW) continue;
            const float wgt = wx[dx] * wy[dy];
            const long off = (long)rx * WW + ry;
#pragma unroll
            for (int c = 0; c < CC; ++c) {
                const long o = (long)(n * CC + c) * HW + off;
                atomicAdd(&imgw[o], v[c] * wgt);
                atomicAdd(&onew[o], wgt);
            }
        }
    }
}

extern "C" void kernel_launch(void* const* d_in, const int* in_sizes, int n_in,
                              void* d_out, int out_size, void* d_ws, size_t ws_size,
                              hipStream_t stream) {
    const float* img = (const float*)d_in[0];
    const float* flo = (const float*)d_in[1];
    float* imgw = (float*)d_out;
    float* onew = imgw + (long)NN * CC * HW;

    // d_out is poisoned 0xAA before every call — zero it (graph-capture-safe).
    hipMemsetAsync(d_out, 0, (size_t)out_size * sizeof(float), stream);

    const int total = NN * HH * WW;          // 8388608
    const int blocks = total / 256;          // 32768
    fwarp_kernel<<<blocks, 256, 0, stream>>>(img, flo, imgw, onew);
}

// Round 2
// 3007.044 us; speedup vs baseline: 3.0604x; 3.0604x over previous
//
#include <hip/hip_runtime.h>
#include <hip/hip_fp16.h>

// ForwardWarp via two-phase binning:
//   Pass A: per source pixel, emit 16B record(s) into per-output-tile bins.
//   Pass B: per tile, accumulate records in LDS, single coalesced out += lds.
// img: (8,3,1024,1024) fp32; flo: (8,2,1024,1024) fp32
// d_out = [imgw (8,3,1024,1024) | onew (8,3,1024,1024)] fp32.

#define NN 8
#define CC 3
#define HH 1024
#define WW 1024
#define HW (HH * WW)
#define NCHW (NN * CC * HW)
#define NBINS (NN * 32 * 32)          // 8192 tiles of 32x32
#define CUR_BYTES (NBINS * 4)

__device__ __forceinline__ unsigned pack2h(float a, float b) {
    __half2 h = __floats2half2_rn(a, b);
    return *reinterpret_cast<unsigned*>(&h);
}
__device__ __forceinline__ float2 unpack2h(unsigned u) {
    __half2 h = *reinterpret_cast<__half2*>(&u);
    return __half22float2(h);
}

// direct global-atomic fallback for one (pixel, tile) when its bin is full
__device__ void apply_fallback(float* imgw, float* onew, int n, int tr, int tc,
                               int ix, int iy, const float wx[2], const float wy[2],
                               float v0, float v1, float v2) {
#pragma unroll
    for (int dx = 0; dx < 2; ++dx) {
        int r = ix + dx;
        if ((unsigned)r >= (unsigned)HH || (r >> 5) != tr) continue;
#pragma unroll
        for (int dy = 0; dy < 2; ++dy) {
            int c = iy + dy;
            if ((unsigned)c >= (unsigned)WW || (c >> 5) != tc) continue;
            float w = wx[dx] * wy[dy];
            long o = (long)(n * CC) * HW + (long)r * WW + c;
            atomicAdd(&imgw[o], v0 * w);
            atomicAdd(&imgw[o + HW], v1 * w);
            atomicAdd(&imgw[o + 2 * HW], v2 * w);
            atomicAdd(&onew[o], w);
            atomicAdd(&onew[o + HW], w);
            atomicAdd(&onew[o + 2 * HW], w);
        }
    }
}

__global__ __launch_bounds__(256) void fwarp_binA(
    const float* __restrict__ img, const float* __restrict__ flo,
    float* __restrict__ imgw, float* __restrict__ onew,
    unsigned* __restrict__ cur, uint4* __restrict__ recs, int CAP)
{
    const int idx = blockIdx.x * 256 + threadIdx.x;   // over N*H*W
    const int wi = idx & (WW - 1);
    const int hi = (idx >> 10) & (HH - 1);
    const int n  = idx >> 20;

    const long pix = (long)hi * WW + wi;
    const long fb = (long)(n * 2) * HW + pix;
    const float yf = flo[fb];         // column shift
    const float xf = flo[fb + HW];    // row shift

    const float x1 = floorf(xf);
    const float y1 = floorf(yf);
    const float fx = xf - x1;
    const float fy = yf - y1;
    const int ix = (int)x1 + hi;      // target row (corner dx=0)
    const int iy = (int)y1 + wi;      // target col (corner dy=0)

    float wx[2], wy[2];
    wx[0] = __expf(-fx * fx);
    wx[1] = __expf(-(fx - 1.0f) * (fx - 1.0f));
    wy[0] = __expf(-fy * fy);
    wy[1] = __expf(-(fy - 1.0f) * (fy - 1.0f));

    const long ib = (long)(n * CC) * HW + pix;
    const float v0 = img[ib];
    const float v1 = img[ib + HW];
    const float v2 = img[ib + 2 * HW];

    // unique tile-rows touched by corner rows {ix, ix+1} ∩ [0,1024)
    int trs[2]; int ntr = 0;
    if ((unsigned)ix < (unsigned)HH) trs[ntr++] = ix >> 5;
    if ((unsigned)(ix + 1) < (unsigned)HH) {
        int t = (ix + 1) >> 5;
        if (ntr == 0 || t != trs[0]) trs[ntr++] = t;
    }
    int tcs[2]; int ntc = 0;
    if ((unsigned)iy < (unsigned)WW) tcs[ntc++] = iy >> 5;
    if ((unsigned)(iy + 1) < (unsigned)WW) {
        int t = (iy + 1) >> 5;
        if (ntc == 0 || t != tcs[0]) tcs[ntc++] = t;
    }

    const unsigned uwx = pack2h(wx[0], wx[1]);
    const unsigned uwy = pack2h(wy[0], wy[1]);
    const unsigned uv01 = pack2h(v0, v1);
    const unsigned uv2 = pack2h(v2, 0.0f) & 0xFFFFu;

    for (int i = 0; i < ntr; ++i) {
        for (int j = 0; j < ntc; ++j) {
            const int tr = trs[i], tc = tcs[j];
            const int lr = ix - (tr << 5);          // [-1..31]
            const int lc = iy - (tc << 5);          // [-1..31]
            const int bin = (n << 10) + (tr << 5) + tc;
            const unsigned slot = atomicAdd(&cur[bin], 1u);
            if ((int)slot < CAP) {
                const unsigned loc = (unsigned)(lr + 1) | ((unsigned)(lc + 1) << 6);
                uint4 rec;
                rec.x = uwx; rec.y = uwy; rec.z = uv01;
                rec.w = uv2 | (loc << 16);
                recs[(size_t)bin * CAP + slot] = rec;
            } else {
                apply_fallback(imgw, onew, n, tr, tc, ix, iy, wx, wy, v0, v1, v2);
            }
        }
    }
}

__global__ __launch_bounds__(256) void fwarp_binB(
    float* __restrict__ imgw, float* __restrict__ onew,
    const unsigned* __restrict__ cur, const uint4* __restrict__ recs, int CAP)
{
    __shared__ float p0[1024], p1[1024], p2[1024], pw[1024];
    const int bin = blockIdx.x;
    const int tid = threadIdx.x;
    const int n = bin >> 10;
    const int tr = (bin >> 5) & 31;
    const int tc = bin & 31;

#pragma unroll
    for (int i = tid; i < 1024; i += 256) {
        p0[i] = 0.0f; p1[i] = 0.0f; p2[i] = 0.0f; pw[i] = 0.0f;
    }
    __syncthreads();

    const int cnt = min((int)cur[bin], CAP);
    const uint4* base = recs + (size_t)bin * CAP;
    for (int i = tid; i < cnt; i += 256) {
        const uint4 rec = base[i];
        const float2 wx = unpack2h(rec.x);
        const float2 wy = unpack2h(rec.y);
        const float2 v01 = unpack2h(rec.z);
        const float v2 = unpack2h(rec.w & 0xFFFFu).x;
        const unsigned loc = rec.w >> 16;
        const int lr = (int)(loc & 63u) - 1;        // [-1..31]
        const int lc = (int)(loc >> 6) - 1;
        const float wxv[2] = {wx.x, wx.y};
        const float wyv[2] = {wy.x, wy.y};
#pragma unroll
        for (int dx = 0; dx < 2; ++dx) {
            const int r = lr + dx;
            if ((unsigned)r >= 32u) continue;
#pragma unroll
            for (int dy = 0; dy < 2; ++dy) {
                const int c = lc + dy;
                if ((unsigned)c >= 32u) continue;
                const float w = wxv[dx] * wyv[dy];
                const int cell = (r << 5) + c;
                atomicAdd(&p0[cell], v01.x * w);
                atomicAdd(&p1[cell], v01.y * w);
                atomicAdd(&p2[cell], v2 * w);
                atomicAdd(&pw[cell], w);
            }
        }
    }
    __syncthreads();

    // unique-writer coalesced flush: out = out + lds (out holds 0 or rare
    // pass-A fallback atomics; pass A completed before pass B on the stream)
#pragma unroll
    for (int i = tid; i < 1024; i += 256) {
        const int gr = (tr << 5) + (i >> 5);
        const int gc = (tc << 5) + (i & 31);
        const long o = (long)(n * CC) * HW + (long)gr * WW + gc;
        imgw[o]          += p0[i];
        imgw[o + HW]     += p1[i];
        imgw[o + 2 * HW] += p2[i];
        const float w = pw[i];
        onew[o]          += w;
        onew[o + HW]     += w;
        onew[o + 2 * HW] += w;
    }
}

extern "C" void kernel_launch(void* const* d_in, const int* in_sizes, int n_in,
                              void* d_out, int out_size, void* d_ws, size_t ws_size,
                              hipStream_t stream) {
    const float* img = (const float*)d_in[0];
    const float* flo = (const float*)d_in[1];
    float* imgw = (float*)d_out;
    float* onew = imgw + (long)NCHW;

    unsigned* cur = (unsigned*)d_ws;
    uint4* recs = (uint4*)((char*)d_ws + CUR_BYTES);

    // bin capacity from available workspace (mean load ~1090/bin, sigma ~33)
    long cap_l = 0;
    if (ws_size > (size_t)CUR_BYTES)
        cap_l = (long)((ws_size - CUR_BYTES) / ((size_t)NBINS * 16));
    int CAP = (int)(cap_l > 2048 ? 2048 : (cap_l < 0 ? 0 : cap_l));

    hipMemsetAsync(d_out, 0, (size_t)out_size * sizeof(float), stream);
    hipMemsetAsync(cur, 0, CUR_BYTES, stream);

    const int total = NN * HH * WW;            // 8388608
    fwarp_binA<<<total / 256, 256, 0, stream>>>(img, flo, imgw, onew, cur, recs, CAP);
    fwarp_binB<<<NBINS, 256, 0, stream>>>(imgw, onew, cur, recs, CAP);
}